// Round 13
// baseline (10582.542 us; speedup 1.0000x reference)
//
#include <hip/hip_runtime.h>
#include <math.h>

#define TENC 256
#define NIE  6
#define LH   68    // h row stride (floats): 16B-aligned rows, 2-way bank alias = free
#define WSTR 68    // weight row stride: jg-offsets land on banks {0,24,16,8} = conflict-free

// ---- LDS: 2*52224 (sW1+sU1) + 528 + 3*17408 (rotating h pool) = 157,200 B ----
__shared__ float sW1[192 * WSTR];   // [(j*3+g)*WSTR + k]
__shared__ float sU1[192 * WSTR];
__shared__ float sHd[132];          // [0:64) Wcv, [64:128) Won
__shared__ float shs[3][64 * LH];   // rotating pool: {h0, h1, free}

// fast activations: v_exp + v_rcp. Proven r4/r6: VALU -13.5pts, absmax identical.
__device__ __forceinline__ float sigm_(float x) {
    return __builtin_amdgcn_rcpf(1.0f + __expf(-x));
}
__device__ __forceinline__ float tanh_(float x) {
    float t = __expf(2.0f * x);
    return (t - 1.0f) * __builtin_amdgcn_rcpf(t + 1.0f);
}

__device__ __forceinline__ void fma4(float& acc, const float4& a, const float4& b) {
    acc = fmaf(a.x, b.x, acc);
    acc = fmaf(a.y, b.y, acc);
    acc = fmaf(a.z, b.z, acc);
    acc = fmaf(a.w, b.w, acc);
}

__device__ __forceinline__ void stage_w1(const float* __restrict__ W1,
                                         const float* __restrict__ U1) {
    for (int s = threadIdx.x; s < 12288; s += 1024) {
        int k = s & 63, row = s >> 6;          // row = g*64 + j (global layout)
        int g = row >> 6, j = row & 63;
        int d = (j * 3 + g) * WSTR + k;        // j-major in LDS
        sW1[d] = W1[s];
        sU1[d] = U1[s];
    }
}

// layer 0: W0 in regs, U0 from global (L2-hot), h from hb (LDS). 1 j x 4 batches.
template<int KIN>
__device__ __forceinline__ void layer0_c(const float* __restrict__ U0,
                                         const float* w0r, const float* w0z,
                                         const float* w0n,          // [KIN] regs
                                         const float* xin,          // [4*KIN] regs
                                         float b_r, float b_z,
                                         float b_nx, float b_nh,
                                         int j, int bl,
                                         const float* __restrict__ hb,
                                         float hn[4])
{
    float ar[4], az[4], anx[4], anh[4];
#pragma unroll
    for (int g = 0; g < 4; ++g) {
        ar[g] = b_r; az[g] = b_z; anx[g] = b_nx; anh[g] = b_nh;
    }
#pragma unroll
    for (int g = 0; g < 4; ++g)
#pragma unroll
        for (int k = 0; k < KIN; ++k) {
            ar[g]  = fmaf(w0r[k], xin[g * KIN + k], ar[g]);
            az[g]  = fmaf(w0z[k], xin[g * KIN + k], az[g]);
            anx[g] = fmaf(w0n[k], xin[g * KIN + k], anx[g]);
        }
    const float* u0 = U0 + (size_t)j * 64;
    const float* hr0 = hb + bl * LH;
#pragma unroll 2
    for (int kc = 0; kc < 64; kc += 4) {
        float4 hv[4];
#pragma unroll
        for (int g = 0; g < 4; ++g)
            hv[g] = *(const float4*)(hr0 + g * (16 * LH) + kc);
        float4 r0 = *(const float4*)(u0 + kc);
        float4 z0 = *(const float4*)(u0 + 4096 + kc);
        float4 n0 = *(const float4*)(u0 + 8192 + kc);
#pragma unroll
        for (int g = 0; g < 4; ++g) {
            fma4(ar[g], r0, hv[g]); fma4(az[g], z0, hv[g]); fma4(anh[g], n0, hv[g]);
        }
    }
#pragma unroll
    for (int g = 0; g < 4; ++g) {
        float hold = hb[(bl + 16 * g) * LH + j];
        float r = sigm_(ar[g]);
        float z = sigm_(az[g]);
        float n = tanh_(fmaf(r, anh[g], anx[g]));
        hn[g] = fmaf(z, hold - n, n);
    }
}

// layer 1: x = xb rows (LDS), h = hb rows (LDS), W1/U1 from LDS. 1 j x 4 batches.
__device__ __forceinline__ void layer1_c(float b_r, float b_z,
                                         float b_nx, float b_nh,
                                         int j, int bl,
                                         const float* __restrict__ xb,
                                         const float* __restrict__ hb,
                                         float hn[4])
{
    float ar[4], az[4], anx[4], anh[4];
#pragma unroll
    for (int g = 0; g < 4; ++g) {
        ar[g] = b_r; az[g] = b_z; anx[g] = b_nx; anh[g] = b_nh;
    }
    const float* wb = sW1 + (j * 3) * WSTR;
    const float* ub = sU1 + (j * 3) * WSTR;
    const float* xr0 = xb + bl * LH;
    const float* hr0 = hb + bl * LH;
#pragma unroll 2
    for (int kc = 0; kc < 64; kc += 4) {
        float4 xv[4], hv[4];
#pragma unroll
        for (int g = 0; g < 4; ++g) {
            xv[g] = *(const float4*)(xr0 + g * (16 * LH) + kc);
            hv[g] = *(const float4*)(hr0 + g * (16 * LH) + kc);
        }
        float4 wr = *(const float4*)(wb + kc);
        float4 wz = *(const float4*)(wb + WSTR + kc);
        float4 wn = *(const float4*)(wb + 2 * WSTR + kc);
        float4 ur = *(const float4*)(ub + kc);
        float4 uz = *(const float4*)(ub + WSTR + kc);
        float4 un = *(const float4*)(ub + 2 * WSTR + kc);
#pragma unroll
        for (int g = 0; g < 4; ++g) {
            fma4(ar[g], wr, xv[g]);  fma4(ar[g], ur, hv[g]);
            fma4(az[g], wz, xv[g]);  fma4(az[g], uz, hv[g]);
            fma4(anx[g], wn, xv[g]); fma4(anh[g], un, hv[g]);
        }
    }
#pragma unroll
    for (int g = 0; g < 4; ++g) {
        float hold = hb[(bl + 16 * g) * LH + j];
        float r = sigm_(ar[g]);
        float z = sigm_(az[g]);
        float n = tanh_(fmaf(r, anh[g], anx[g]));
        hn[g] = fmaf(z, hold - n, n);
    }
}

// VGPR model (r2..r12): cap = 512 / (waves/SIMD implied by launch_bounds);
// the DEFAULT 2nd arg targets 2 blocks/CU. 1024-thread default -> 32 waves
// -> 8/SIMD -> 64 VGPR (r12: 8.4 GB spills at 48% occupancy). (1024,1) ->
// 16 waves -> 4/SIMD -> 128 cap; per-lane liveness ~100 regs fits.
extern "C" __global__ void __launch_bounds__(1024, 1)
ccseq_kernel(const float* __restrict__ x, const int* __restrict__ p_tlen,
             const float* __restrict__ eW0, const float* __restrict__ eU0,
             const float* __restrict__ eBi0, const float* __restrict__ eBh0,
             const float* __restrict__ eW1, const float* __restrict__ eU1,
             const float* __restrict__ eBi1, const float* __restrict__ eBh1,
             const float* __restrict__ dW0, const float* __restrict__ dU0,
             const float* __restrict__ dBi0, const float* __restrict__ dBh0,
             const float* __restrict__ dW1, const float* __restrict__ dU1,
             const float* __restrict__ dBi1, const float* __restrict__ dBh1,
             const float* __restrict__ Won, const float* __restrict__ bon,
             const float* __restrict__ Wcv, const float* __restrict__ bcv,
             float* __restrict__ out)
{
    const int tid  = threadIdx.x;
    const int lane = tid & 63;
    const int wv   = tid >> 6;          // 0..15
    const int jg   = lane >> 4;         // 0..3
    const int bl   = lane & 15;         // 0..15
    const int j    = wv * 4 + jg;       // this lane's single hidden unit
    const int tlen = p_tlen[0];

    if (tid < 64) { sHd[tid] = Wcv[tid]; sHd[64 + tid] = Won[tid]; }
    for (int i = tid; i < 64 * LH; i += 1024) {
        shs[0][i] = 0.0f; shs[1][i] = 0.0f; shs[2][i] = 0.0f;
    }
    stage_w1(eW1, eU1);
    __syncthreads();

    // ---- hoisted per-lane constants (encoder) ----
    float w0r[NIE], w0z[NIE], w0n[NIE];
#pragma unroll
    for (int k = 0; k < NIE; ++k) {
        w0r[k] = eW0[j * NIE + k];
        w0z[k] = eW0[(64 + j) * NIE + k];
        w0n[k] = eW0[(128 + j) * NIE + k];
    }
    const float eb_r  = eBi0[j] + eBh0[j];
    const float eb_z  = eBi0[64 + j] + eBh0[64 + j];
    const float eb_nx = eBi0[128 + j];
    const float eb_nh = eBh0[128 + j];
    const float e1_r  = eBi1[j] + eBh1[j];
    const float e1_z  = eBi1[64 + j] + eBh1[64 + j];
    const float e1_nx = eBi1[128 + j];
    const float e1_nh = eBh1[128 + j];

    const size_t bstr = (size_t)TENC * NIE;
    const float* xb[4];
#pragma unroll
    for (int g = 0; g < 4; ++g)
        xb[g] = x + (size_t)(blockIdx.x * 64 + bl + 16 * g) * bstr;

    // ---------------- encoder prologue: h0(0) = gru0(x(0), 0) ----------------
    float xc[4 * NIE];
    float hn[4], hn0[4];
#pragma unroll
    for (int g = 0; g < 4; ++g)
#pragma unroll
        for (int k = 0; k < NIE; ++k) xc[g * NIE + k] = xb[g][k];

    layer0_c<NIE>(eU0, w0r, w0z, w0n, xc, eb_r, eb_z, eb_nx, eb_nh,
                  j, bl, shs[0] /*zeros*/, hn0);
#pragma unroll
    for (int g = 0; g < 4; ++g)
        shs[1][(bl + 16 * g) * LH + j] = hn0[g];
    __syncthreads();                            // h0(0) published
    int ih0 = 1, ih1 = 2, ifr = 0;              // h1(-1)=zeros in shs[2]

    // ---------------- encoder: 2 barriers/step ----------------
    for (int t = 0; t < TENC; ++t) {
        if (t + 1 < TENC) {
#pragma unroll
            for (int g = 0; g < 4; ++g)
#pragma unroll
                for (int k = 0; k < NIE; ++k)
                    xc[g * NIE + k] = xb[g][(t + 1) * NIE + k];
        }

        layer1_c(e1_r, e1_z, e1_nx, e1_nh, j, bl, shs[ih0], shs[ih1], hn);

        // separate the two layers' register-pressure regions (r9 spill fix)
        __builtin_amdgcn_sched_barrier(0);

        if (t + 1 < TENC) {
            layer0_c<NIE>(eU0, w0r, w0z, w0n, xc, eb_r, eb_z, eb_nx, eb_nh,
                          j, bl, shs[ih0], hn0);
#pragma unroll
            for (int g = 0; g < 4; ++g)
                shs[ifr][(bl + 16 * g) * LH + j] = hn0[g];
        }
        __syncthreads();                       // A: h0(t+1) published; h1 reads drained
#pragma unroll
        for (int g = 0; g < 4; ++g)
            shs[ih1][(bl + 16 * g) * LH + j] = hn[g];   // h1(t) in place
        __syncthreads();                       // B: h1(t) published

        if (t + 1 < TENC) { int o = ih0; ih0 = ifr; ifr = o; }
    }
    // state: shs[ih0]=h0(255), shs[ih1]=h1(255), shs[ifr] free

    // ---------------- swap to decoder weights ----------------
    stage_w1(dW1, dU1);                        // safe: sW1/sU1 reads drained by barrier B
    const float v0r = dW0[j], v0z = dW0[64 + j], v0n = dW0[128 + j];
    const float db_r  = dBi0[j] + dBh0[j];
    const float db_z  = dBi0[64 + j] + dBh0[64 + j];
    const float db_nx = dBi0[128 + j];
    const float db_nh = dBh0[128 + j];
    const float d1_r  = dBi1[j] + dBh1[j];
    const float d1_z  = dBi1[64 + j] + dBh1[64 + j];
    const float d1_nx = dBi1[128 + j];
    const float d1_nh = dBh1[128 + j];
    const float hbc = bcv[0], hbo = bon[0];
    __syncthreads();

    // ---------------- decoder: 2 barriers/step (rotating buffers) ----------------
    float prev[4] = {0.0f, 0.0f, 0.0f, 0.0f};
    for (int t = 0; t < tlen; ++t) {
        layer0_c<1>(dU0, &v0r, &v0z, &v0n, prev, db_r, db_z, db_nx, db_nh,
                    j, bl, shs[ih0], hn);
#pragma unroll
        for (int g = 0; g < 4; ++g)
            shs[ifr][(bl + 16 * g) * LH + j] = hn[g];
        __syncthreads();                       // A: h0_dec(t) published

        layer1_c(d1_r, d1_z, d1_nx, d1_nh, j, bl, shs[ifr], shs[ih1], hn);
#pragma unroll
        for (int g = 0; g < 4; ++g)
            shs[ih0][(bl + 16 * g) * LH + j] = hn[g];   // h1_dec(t) into dead h0-old
        __syncthreads();                       // B: h1_dec(t) published

        // heads: every lane computes its own 4 batches (no exchange needed)
        float cv[4] = {hbc, hbc, hbc, hbc};
        float lg[4] = {hbo, hbo, hbo, hbo};
        const float* hr0 = shs[ih0] + bl * LH;
#pragma unroll 2
        for (int kc = 0; kc < 64; kc += 4) {
            float4 wc = *(const float4*)(sHd + kc);
            float4 wo = *(const float4*)(sHd + 64 + kc);
#pragma unroll
            for (int g = 0; g < 4; ++g) {
                float4 h4 = *(const float4*)(hr0 + g * (16 * LH) + kc);
                fma4(cv[g], wc, h4);
                fma4(lg[g], wo, h4);
            }
        }
#pragma unroll
        for (int g = 0; g < 4; ++g)
            prev[g] = (lg[g] > 0.0f) ? cv[g] : 0.0f;   // sigmoid(lg)>0.5 <=> lg>0
        if (tid < 16) {
#pragma unroll
            for (int g = 0; g < 4; ++g)
                out[(size_t)(blockIdx.x * 64 + bl + 16 * g) * tlen + t] = prev[g];
        }
        int o0 = ih0, o1 = ih1;
        ih0 = ifr; ih1 = o0; ifr = o1;
    }
}

extern "C" void kernel_launch(void* const* d_in, const int* in_sizes, int n_in,
                              void* d_out, int out_size, void* d_ws, size_t ws_size,
                              hipStream_t stream)
{
    (void)n_in; (void)out_size; (void)d_ws; (void)ws_size;
    const float* x    = (const float*)d_in[0];
    const int*   tl   = (const int*)d_in[1];
    const float* eW0  = (const float*)d_in[2];
    const float* eU0  = (const float*)d_in[3];
    const float* eBi0 = (const float*)d_in[4];
    const float* eBh0 = (const float*)d_in[5];
    const float* eW1  = (const float*)d_in[6];
    const float* eU1  = (const float*)d_in[7];
    const float* eBi1 = (const float*)d_in[8];
    const float* eBh1 = (const float*)d_in[9];
    const float* dW0  = (const float*)d_in[10];
    const float* dU0  = (const float*)d_in[11];
    const float* dBi0 = (const float*)d_in[12];
    const float* dBh0 = (const float*)d_in[13];
    const float* dW1  = (const float*)d_in[14];
    const float* dU1  = (const float*)d_in[15];
    const float* dBi1 = (const float*)d_in[16];
    const float* dBh1 = (const float*)d_in[17];
    const float* Won  = (const float*)d_in[18];
    const float* bon  = (const float*)d_in[19];
    const float* Wcv  = (const float*)d_in[20];
    const float* bcv  = (const float*)d_in[21];

    const int B    = in_sizes[0] / (TENC * NIE);  // 16384
    const int nblk = B / 64;                      // 256 blocks, 1/CU

    ccseq_kernel<<<dim3(nblk), dim3(1024), 0, stream>>>(
        x, tl, eW0, eU0, eBi0, eBh0, eW1, eU1, eBi1, eBh1,
        dW0, dU0, dBi0, dBh0, dW1, dU1, dBi1, dBh1,
        Won, bon, Wcv, bcv, (float*)d_out);
}

// Round 14
// 8389.053 us; speedup vs baseline: 1.2615x; 1.2615x over previous
//
#include <hip/hip_runtime.h>
#include <math.h>

#define TENC 256
#define NIE  6
#define LH   68    // h row stride (floats): 16B-aligned rows, 2-way bank alias = free
#define WSTR 68    // weight row stride: jg-offsets land on banks {0,24,16,8} = conflict-free

// ---- LDS: 2*52224 (sW1+sU1) + 528 + 3*17408 (rotating h pool) = 157,200 B ----
__shared__ float sW1[192 * WSTR];   // [(j*3+g)*WSTR + k]
__shared__ float sU1[192 * WSTR];
__shared__ float sHd[132];          // [0:64) Wcv, [64:128) Won
__shared__ float shs[3][64 * LH];   // rotating pool: {h0, h1, free}

// fast activations: v_exp + v_rcp. Proven r4/r6: VALU -13.5pts, absmax identical.
__device__ __forceinline__ float sigm_(float x) {
    return __builtin_amdgcn_rcpf(1.0f + __expf(-x));
}
__device__ __forceinline__ float tanh_(float x) {
    float t = __expf(2.0f * x);
    return (t - 1.0f) * __builtin_amdgcn_rcpf(t + 1.0f);
}

__device__ __forceinline__ void fma4(float& acc, const float4& a, const float4& b) {
    acc = fmaf(a.x, b.x, acc);
    acc = fmaf(a.y, b.y, acc);
    acc = fmaf(a.z, b.z, acc);
    acc = fmaf(a.w, b.w, acc);
}

__device__ __forceinline__ void stage_w1(const float* __restrict__ W1,
                                         const float* __restrict__ U1) {
    for (int s = threadIdx.x; s < 12288; s += 512) {
        int k = s & 63, row = s >> 6;          // row = g*64 + j (global layout)
        int g = row >> 6, j = row & 63;
        int d = (j * 3 + g) * WSTR + k;        // j-major in LDS
        sW1[d] = W1[s];
        sU1[d] = U1[s];
    }
}

// layer 0: W0 in regs, U0 from global (L2-hot), h from hb (LDS). 2 j's x 4 batches.
// Inner unroll MUST stay 2 — backend pins 128 VGPR (r4/r5); unroll 4 spills.
template<int KIN>
__device__ __forceinline__ void layer0_c(const float* __restrict__ U0,
                                         const float* w0r, const float* w0z,
                                         const float* w0n,          // [2*KIN] regs
                                         const float* xin,          // [4*KIN] regs
                                         const float* b_r, const float* b_z,
                                         const float* b_nx, const float* b_nh,
                                         int jB, int bl,
                                         const float* __restrict__ hb,
                                         float hn[2][4])
{
    float ar[2][4], az[2][4], anx[2][4], anh[2][4];
#pragma unroll
    for (int g = 0; g < 4; ++g) {
#pragma unroll
        for (int jj = 0; jj < 2; ++jj) {
            ar[jj][g] = b_r[jj]; az[jj][g] = b_z[jj];
            anx[jj][g] = b_nx[jj]; anh[jj][g] = b_nh[jj];
        }
    }
#pragma unroll
    for (int jj = 0; jj < 2; ++jj)
#pragma unroll
        for (int g = 0; g < 4; ++g)
#pragma unroll
            for (int k = 0; k < KIN; ++k) {
                ar[jj][g]  = fmaf(w0r[jj * KIN + k], xin[g * KIN + k], ar[jj][g]);
                az[jj][g]  = fmaf(w0z[jj * KIN + k], xin[g * KIN + k], az[jj][g]);
                anx[jj][g] = fmaf(w0n[jj * KIN + k], xin[g * KIN + k], anx[jj][g]);
            }
    const float* u0 = U0 + (size_t)jB * 64;
    const float* u1 = U0 + (size_t)(jB + 1) * 64;
    const float* hr0 = hb + bl * LH;
#pragma unroll 2
    for (int kc = 0; kc < 64; kc += 4) {
        float4 hv[4];
#pragma unroll
        for (int g = 0; g < 4; ++g)
            hv[g] = *(const float4*)(hr0 + g * (16 * LH) + kc);
        float4 r0 = *(const float4*)(u0 + kc);
        float4 z0 = *(const float4*)(u0 + 4096 + kc);
        float4 n0 = *(const float4*)(u0 + 8192 + kc);
        float4 r1 = *(const float4*)(u1 + kc);
        float4 z1 = *(const float4*)(u1 + 4096 + kc);
        float4 n1 = *(const float4*)(u1 + 8192 + kc);
#pragma unroll
        for (int g = 0; g < 4; ++g) {
            fma4(ar[0][g], r0, hv[g]); fma4(az[0][g], z0, hv[g]); fma4(anh[0][g], n0, hv[g]);
            fma4(ar[1][g], r1, hv[g]); fma4(az[1][g], z1, hv[g]); fma4(anh[1][g], n1, hv[g]);
        }
    }
#pragma unroll
    for (int g = 0; g < 4; ++g) {
        float2 ho = *(const float2*)(hb + (bl + 16 * g) * LH + jB);
        float hold[2] = {ho.x, ho.y};
#pragma unroll
        for (int jj = 0; jj < 2; ++jj) {
            float r = sigm_(ar[jj][g]);
            float z = sigm_(az[jj][g]);
            float n = tanh_(fmaf(r, anh[jj][g], anx[jj][g]));
            hn[jj][g] = fmaf(z, hold[jj] - n, n);
        }
    }
}

// layer 1: x = xb rows (LDS), h = hb rows (LDS), W1/U1 from LDS (r6-proven form).
__device__ __forceinline__ void layer1_c(const float* b_r, const float* b_z,
                                         const float* b_nx, const float* b_nh,
                                         int jB, int bl,
                                         const float* __restrict__ xb,
                                         const float* __restrict__ hb,
                                         float hn[2][4])
{
    float ar[2][4], az[2][4], anx[2][4], anh[2][4];
#pragma unroll
    for (int g = 0; g < 4; ++g) {
#pragma unroll
        for (int jj = 0; jj < 2; ++jj) {
            ar[jj][g] = b_r[jj]; az[jj][g] = b_z[jj];
            anx[jj][g] = b_nx[jj]; anh[jj][g] = b_nh[jj];
        }
    }
    const float* wb0 = sW1 + (jB * 3) * WSTR;
    const float* wb1 = sW1 + ((jB + 1) * 3) * WSTR;
    const float* ub0 = sU1 + (jB * 3) * WSTR;
    const float* ub1 = sU1 + ((jB + 1) * 3) * WSTR;
    const float* xr0 = xb + bl * LH;
    const float* hr0 = hb + bl * LH;
#pragma unroll 2
    for (int kc = 0; kc < 64; kc += 4) {
        float4 xv[4], hv[4];
#pragma unroll
        for (int g = 0; g < 4; ++g) {
            xv[g] = *(const float4*)(xr0 + g * (16 * LH) + kc);
            hv[g] = *(const float4*)(hr0 + g * (16 * LH) + kc);
        }
        float4 wr0 = *(const float4*)(wb0 + kc);
        float4 wz0 = *(const float4*)(wb0 + WSTR + kc);
        float4 wn0 = *(const float4*)(wb0 + 2 * WSTR + kc);
        float4 ur0 = *(const float4*)(ub0 + kc);
        float4 uz0 = *(const float4*)(ub0 + WSTR + kc);
        float4 un0 = *(const float4*)(ub0 + 2 * WSTR + kc);
        float4 wr1 = *(const float4*)(wb1 + kc);
        float4 wz1 = *(const float4*)(wb1 + WSTR + kc);
        float4 wn1 = *(const float4*)(wb1 + 2 * WSTR + kc);
        float4 ur1 = *(const float4*)(ub1 + kc);
        float4 uz1 = *(const float4*)(ub1 + WSTR + kc);
        float4 un1 = *(const float4*)(ub1 + 2 * WSTR + kc);
#pragma unroll
        for (int g = 0; g < 4; ++g) {
            fma4(ar[0][g], wr0, xv[g]);  fma4(ar[0][g], ur0, hv[g]);
            fma4(az[0][g], wz0, xv[g]);  fma4(az[0][g], uz0, hv[g]);
            fma4(anx[0][g], wn0, xv[g]); fma4(anh[0][g], un0, hv[g]);
            fma4(ar[1][g], wr1, xv[g]);  fma4(ar[1][g], ur1, hv[g]);
            fma4(az[1][g], wz1, xv[g]);  fma4(az[1][g], uz1, hv[g]);
            fma4(anx[1][g], wn1, xv[g]); fma4(anh[1][g], un1, hv[g]);
        }
    }
#pragma unroll
    for (int g = 0; g < 4; ++g) {
        float2 ho = *(const float2*)(hb + (bl + 16 * g) * LH + jB);
        float hold[2] = {ho.x, ho.y};
#pragma unroll
        for (int jj = 0; jj < 2; ++jj) {
            float r = sigm_(ar[jj][g]);
            float z = sigm_(az[jj][g]);
            float n = tanh_(fmaf(r, anh[jj][g], anx[jj][g]));
            hn[jj][g] = fmaf(z, hold[jj] - n, n);
        }
    }
}

// Balanced-segment schedule (r14): r10's step was [layer1+layer0] A [4 stores] B
// — the A->B interval was EMPTY (back-to-back drains every step). Now:
// seg1 = layer1(t); A; seg2 = store h1 + load x + layer0(t+1) + store h0; B.
// Both intervals contain compute; barrier memory semantics keep the two
// layers' register regions separate (no sched_barrier needed -> r8 spill
// hazard structurally gone). Occupancy map (r3/r12/r13): 512thr = 8 waves
// @128 VGPR, always 1 block/CU; 1024thr = 16 waves @64 VGPR (spills) —
// 512thr/128reg is the better equilibrium.
extern "C" __global__ void __launch_bounds__(512, 2)
ccseq_kernel(const float* __restrict__ x, const int* __restrict__ p_tlen,
             const float* __restrict__ eW0, const float* __restrict__ eU0,
             const float* __restrict__ eBi0, const float* __restrict__ eBh0,
             const float* __restrict__ eW1, const float* __restrict__ eU1,
             const float* __restrict__ eBi1, const float* __restrict__ eBh1,
             const float* __restrict__ dW0, const float* __restrict__ dU0,
             const float* __restrict__ dBi0, const float* __restrict__ dBh0,
             const float* __restrict__ dW1, const float* __restrict__ dU1,
             const float* __restrict__ dBi1, const float* __restrict__ dBh1,
             const float* __restrict__ Won, const float* __restrict__ bon,
             const float* __restrict__ Wcv, const float* __restrict__ bcv,
             float* __restrict__ out)
{
    const int tid  = threadIdx.x;
    const int lane = tid & 63;
    const int wv   = tid >> 6;          // 0..7
    const int jg   = lane >> 4;         // 0..3
    const int bl   = lane & 15;         // 0..15
    const int jB   = wv * 8 + jg * 2;   // this lane's 2 hidden units
    const int tlen = p_tlen[0];

    if (tid < 64) { sHd[tid] = Wcv[tid]; sHd[64 + tid] = Won[tid]; }
    for (int i = tid; i < 64 * LH; i += 512) {
        shs[0][i] = 0.0f; shs[1][i] = 0.0f; shs[2][i] = 0.0f;
    }
    stage_w1(eW1, eU1);
    __syncthreads();

    // ---- hoisted per-lane constants (encoder) ----
    float w0r[2 * NIE], w0z[2 * NIE], w0n[2 * NIE];
#pragma unroll
    for (int jj = 0; jj < 2; ++jj)
#pragma unroll
        for (int k = 0; k < NIE; ++k) {
            w0r[jj * NIE + k] = eW0[(jB + jj) * NIE + k];
            w0z[jj * NIE + k] = eW0[(64 + jB + jj) * NIE + k];
            w0n[jj * NIE + k] = eW0[(128 + jB + jj) * NIE + k];
        }
    float eb_r[2], eb_z[2], eb_nx[2], eb_nh[2];
    float e1_r[2], e1_z[2], e1_nx[2], e1_nh[2];
#pragma unroll
    for (int jj = 0; jj < 2; ++jj) {
        int j = jB + jj;
        eb_r[jj]  = eBi0[j] + eBh0[j];
        eb_z[jj]  = eBi0[64 + j] + eBh0[64 + j];
        eb_nx[jj] = eBi0[128 + j];
        eb_nh[jj] = eBh0[128 + j];
        e1_r[jj]  = eBi1[j] + eBh1[j];
        e1_z[jj]  = eBi1[64 + j] + eBh1[64 + j];
        e1_nx[jj] = eBi1[128 + j];
        e1_nh[jj] = eBh1[128 + j];
    }

    const size_t bstr = (size_t)TENC * NIE;
    const float* xb[4];
#pragma unroll
    for (int g = 0; g < 4; ++g)
        xb[g] = x + (size_t)(blockIdx.x * 64 + bl + 16 * g) * bstr;

    // ---------------- encoder prologue: h0(0) = gru0(x(0), 0) ----------------
    float xc[4 * NIE];
    float hn[2][4], hn0[2][4];
#pragma unroll
    for (int g = 0; g < 4; ++g)
#pragma unroll
        for (int k = 0; k < NIE; ++k) xc[g * NIE + k] = xb[g][k];

    layer0_c<NIE>(eU0, w0r, w0z, w0n, xc, eb_r, eb_z, eb_nx, eb_nh,
                  jB, bl, shs[0] /*zeros*/, hn0);
#pragma unroll
    for (int g = 0; g < 4; ++g)
        *(float2*)(shs[1] + (bl + 16 * g) * LH + jB) = make_float2(hn0[0][g], hn0[1][g]);
    __syncthreads();                            // h0(0) published
    int ih0 = 1, ih1 = 2, ifr = 0;              // h1(-1)=zeros in shs[2]

    // ---------------- encoder: 2 balanced segments per step ----------------
    // seg1: layer1(t){shs[ih0],shs[ih1]}
    // A (drains ih0/ih1 reads)
    // seg2: h1(t)->shs[ih1] | x(t+1) load | layer0(t+1){shs[ih0]} -> shs[ifr]
    // B (publish h1(t), h0(t+1))
    for (int t = 0; t < TENC; ++t) {
        layer1_c(e1_r, e1_z, e1_nx, e1_nh, jB, bl, shs[ih0], shs[ih1], hn);
        __syncthreads();                       // A
#pragma unroll
        for (int g = 0; g < 4; ++g)
            *(float2*)(shs[ih1] + (bl + 16 * g) * LH + jB) =
                make_float2(hn[0][g], hn[1][g]);   // h1(t) in place

        if (t + 1 < TENC) {
#pragma unroll
            for (int g = 0; g < 4; ++g)
#pragma unroll
                for (int k = 0; k < NIE; ++k)
                    xc[g * NIE + k] = xb[g][(t + 1) * NIE + k];
            layer0_c<NIE>(eU0, w0r, w0z, w0n, xc, eb_r, eb_z, eb_nx, eb_nh,
                          jB, bl, shs[ih0], hn0);
#pragma unroll
            for (int g = 0; g < 4; ++g)
                *(float2*)(shs[ifr] + (bl + 16 * g) * LH + jB) =
                    make_float2(hn0[0][g], hn0[1][g]);
        }
        __syncthreads();                       // B: h1(t) and h0(t+1) published

        if (t + 1 < TENC) { int o = ih0; ih0 = ifr; ifr = o; }
    }
    // state: shs[ih0]=h0(255), shs[ih1]=h1(255), shs[ifr] free

    // ---------------- swap to decoder weights ----------------
    stage_w1(dW1, dU1);                        // safe: sW1/sU1 reads drained by barrier A/B
    float v0r[2], v0z[2], v0n[2];
    float db_r[2], db_z[2], db_nx[2], db_nh[2];
    float d1_r[2], d1_z[2], d1_nx[2], d1_nh[2];
#pragma unroll
    for (int jj = 0; jj < 2; ++jj) {
        int j = jB + jj;
        v0r[jj] = dW0[j]; v0z[jj] = dW0[64 + j]; v0n[jj] = dW0[128 + j];
        db_r[jj]  = dBi0[j] + dBh0[j];
        db_z[jj]  = dBi0[64 + j] + dBh0[64 + j];
        db_nx[jj] = dBi0[128 + j];
        db_nh[jj] = dBh0[128 + j];
        d1_r[jj]  = dBi1[j] + dBh1[j];
        d1_z[jj]  = dBi1[64 + j] + dBh1[64 + j];
        d1_nx[jj] = dBi1[128 + j];
        d1_nh[jj] = dBh1[128 + j];
    }
    const float hbc = bcv[0], hbo = bon[0];
    __syncthreads();

    // ---------------- decoder: 2 barriers/step (rotating buffers, r10) ----------------
    // layer0 -> shs[ifr] | A (drains ih0 reads) |
    // layer1{shs[ifr], shs[ih1]} -> shs[ih0] (dead) + heads | B
    float prev[4] = {0.0f, 0.0f, 0.0f, 0.0f};
    for (int t = 0; t < tlen; ++t) {
        layer0_c<1>(dU0, v0r, v0z, v0n, prev, db_r, db_z, db_nx, db_nh,
                    jB, bl, shs[ih0], hn);
#pragma unroll
        for (int g = 0; g < 4; ++g)
            *(float2*)(shs[ifr] + (bl + 16 * g) * LH + jB) =
                make_float2(hn[0][g], hn[1][g]);
        __syncthreads();                       // A: h0_dec(t) published

        layer1_c(d1_r, d1_z, d1_nx, d1_nh, jB, bl, shs[ifr], shs[ih1], hn);
#pragma unroll
        for (int g = 0; g < 4; ++g)
            *(float2*)(shs[ih0] + (bl + 16 * g) * LH + jB) =
                make_float2(hn[0][g], hn[1][g]);   // h1_dec(t) into dead h0-old
        __syncthreads();                       // B: h1_dec(t) published

        // heads: every lane computes its own 4 batches (no exchange needed)
        float cv[4] = {hbc, hbc, hbc, hbc};
        float lg[4] = {hbo, hbo, hbo, hbo};
        const float* hr0 = shs[ih0] + bl * LH;
#pragma unroll 2
        for (int kc = 0; kc < 64; kc += 4) {
            float4 wc = *(const float4*)(sHd + kc);
            float4 wo = *(const float4*)(sHd + 64 + kc);
#pragma unroll
            for (int g = 0; g < 4; ++g) {
                float4 h4 = *(const float4*)(hr0 + g * (16 * LH) + kc);
                fma4(cv[g], wc, h4);
                fma4(lg[g], wo, h4);
            }
        }
#pragma unroll
        for (int g = 0; g < 4; ++g)
            prev[g] = (lg[g] > 0.0f) ? cv[g] : 0.0f;   // sigmoid(lg)>0.5 <=> lg>0
        if (tid < 16) {
#pragma unroll
            for (int g = 0; g < 4; ++g)
                out[(size_t)(blockIdx.x * 64 + bl + 16 * g) * tlen + t] = prev[g];
        }
        int o0 = ih0, o1 = ih1;
        ih0 = ifr; ih1 = o0; ifr = o1;
    }
}

extern "C" void kernel_launch(void* const* d_in, const int* in_sizes, int n_in,
                              void* d_out, int out_size, void* d_ws, size_t ws_size,
                              hipStream_t stream)
{
    (void)n_in; (void)out_size; (void)d_ws; (void)ws_size;
    const float* x    = (const float*)d_in[0];
    const int*   tl   = (const int*)d_in[1];
    const float* eW0  = (const float*)d_in[2];
    const float* eU0  = (const float*)d_in[3];
    const float* eBi0 = (const float*)d_in[4];
    const float* eBh0 = (const float*)d_in[5];
    const float* eW1  = (const float*)d_in[6];
    const float* eU1  = (const float*)d_in[7];
    const float* eBi1 = (const float*)d_in[8];
    const float* eBh1 = (const float*)d_in[9];
    const float* dW0  = (const float*)d_in[10];
    const float* dU0  = (const float*)d_in[11];
    const float* dBi0 = (const float*)d_in[12];
    const float* dBh0 = (const float*)d_in[13];
    const float* dW1  = (const float*)d_in[14];
    const float* dU1  = (const float*)d_in[15];
    const float* dBi1 = (const float*)d_in[16];
    const float* dBh1 = (const float*)d_in[17];
    const float* Won  = (const float*)d_in[18];
    const float* bon  = (const float*)d_in[19];
    const float* Wcv  = (const float*)d_in[20];
    const float* bcv  = (const float*)d_in[21];

    const int B    = in_sizes[0] / (TENC * NIE);  // 16384
    const int nblk = B / 64;                      // 256 blocks, 1/CU

    ccseq_kernel<<<dim3(nblk), dim3(512), 0, stream>>>(
        x, tl, eW0, eU0, eBi0, eBh0, eW1, eU1, eBi1, eBh1,
        dW0, dU0, dBi0, dBh0, dW1, dU1, dBi1, dBh1,
        Won, bon, Wcv, bcv, (float*)d_out);
}